// Round 7
// baseline (345.138 us; speedup 1.0000x reference)
//
#include <hip/hip_runtime.h>

// CausalAttention: x[4,2048,1024] f32, Wq/Wk/Wv [1024,1024] f32 -> out [4,2048,1024] f32
// Round 7: 256^2 GEMM with 4-slot k-half ring LDS (k-major, bank-conflict-free by
// construction), counted vmcnt(4) per K-tile (stage 3 half-slots ahead), per-phase
// {stage || ds_read -> barrier -> setprio+16 MFMA -> barrier}, chunked XCD swizzle.

using f32x4 = __attribute__((ext_vector_type(4))) float;
using s16x8 = __attribute__((ext_vector_type(8))) short;

#define CTX 2048
#define DIM 1024
#define NB 4

__device__ __forceinline__ short f2bf(float f) {
  union { float f; unsigned u; } v; v.f = f;
  unsigned r = (v.u + 0x7fffu + ((v.u >> 16) & 1u)) >> 16;
  return (short)r;
}

__device__ __forceinline__ void async16(const void* g, void* l) {
  __builtin_amdgcn_global_load_lds(
      (const __attribute__((address_space(1))) void*)g,
      (__attribute__((address_space(3))) void*)l, 16, 0, 0);
}

#define FENCE_BAR()                              \
  do {                                           \
    asm volatile("" ::: "memory");               \
    __builtin_amdgcn_s_barrier();                \
    asm volatile("" ::: "memory");               \
  } while (0)

// ---------------- convert kernels ----------------

__global__ __launch_bounds__(256) void cvt_x(const float* __restrict__ in,
                                             short* __restrict__ out, long n8) {
  long i = (long)blockIdx.x * 256 + threadIdx.x;
  if (i >= n8) return;
  const float4* p = (const float4*)in;
  float4 a = p[i * 2], b = p[i * 2 + 1];
  short o[8];
  o[0] = f2bf(a.x); o[1] = f2bf(a.y); o[2] = f2bf(a.z); o[3] = f2bf(a.w);
  o[4] = f2bf(b.x); o[5] = f2bf(b.y); o[6] = f2bf(b.z); o[7] = f2bf(b.w);
  *(int4*)&out[i * 8] = *(int4*)o;
}

// W [1024][1024] f32 -> WT [3072 rows][1024 k] bf16 (stacked Wq^T,Wk^T,Wv^T)
__global__ __launch_bounds__(256) void cvt_wT(const float* __restrict__ Wq,
                                              const float* __restrict__ Wk,
                                              const float* __restrict__ Wv,
                                              short* __restrict__ WT) {
  int z = blockIdx.z;
  const float* W = (z == 0) ? Wq : (z == 1) ? Wk : Wv;
  short* o = WT + (long)z * DIM * DIM;
  __shared__ float t[32][33];
  int n0 = blockIdx.x * 32, k0 = blockIdx.y * 32;
  int tx = threadIdx.x, ty = threadIdx.y;  // block (32,8)
  #pragma unroll
  for (int j = 0; j < 4; ++j)
    t[ty + j * 8][tx] = W[(long)(k0 + ty + j * 8) * DIM + n0 + tx];
  __syncthreads();
  #pragma unroll
  for (int j = 0; j < 4; ++j)
    o[(long)(n0 + ty + j * 8) * DIM + k0 + tx] = f2bf(t[tx][ty + j * 8]);
}

// ---------------- 256^2 GEMM (BT form): C[M,N] = A[M,K] * B[N,K]^T ----------------
// 8 waves (2M x 4N), per-wave C 128x64 = acc[8][4].
// LDS: A-ring 4 slots @0, B-ring 4 slots @65536; slot = 16KB = one 32-k half-tile,
// k-major layout: addr = kgrp*4096 + row*16 (row = M-row for A, N-row for B).
// ds_read_b128: 16 lanes (frow) read contiguous 256B per kgrp -> 2 lanes/bank (free).
// Stage: thread tid -> (row = tid&255, kgrp = (tid>>8)+2s), dest = tid*16 + s*8192
// (linear per wave, as global_load_lds requires); source = row*ldb + h*64 + kgrp*16.
// Schedule per K-tile t (k-halves h0=2t, h1=2t+1), 4 phases:
//  p1 (ks0,nh0): stage A[2t+3]; read aA[8] + bB[2](nh0); bar; MFMA; bar
//  p2 (ks0,nh1): stage B[2t+3]; read bB[2](nh1);          bar; MFMA; bar
//  p3 (ks1,nh0): stage A[2t+4]; read aA[8] + bB[2](nh0);  bar; MFMA; bar
//  p4 (ks1,nh1): stage B[2t+4]; read bB[2](nh1);          bar; MFMA; vmcnt(4|0); bar
// Ledger: slot h consumed at group floor(h/2) was staged 4-6 stage-ops before the
// preceding boundary check -> landed under vmcnt(4) (<=2 slot-matrices in flight).
// Overwrites (h+4 over h) happen >=2 barriers after h's last ds_read. WAR-safe.
#define MFMA_PHASE(nh)                                                       \
  do {                                                                       \
    __builtin_amdgcn_s_setprio(1);                                           \
    _Pragma("unroll") for (int mi = 0; mi < 8; ++mi) {                       \
      _Pragma("unroll") for (int ni = 0; ni < 2; ++ni) {                     \
        acc[mi][(nh) * 2 + ni] = __builtin_amdgcn_mfma_f32_16x16x32_bf16(    \
            aA[mi], bB[ni], acc[mi][(nh) * 2 + ni], 0, 0, 0);                \
      }                                                                      \
    }                                                                        \
    __builtin_amdgcn_s_setprio(0);                                           \
  } while (0)

template <int MODE, bool CSKIP, bool KLIM, bool SWZGRID>
__global__ __launch_bounds__(512, 1) void gemm256(const short* __restrict__ A,
                                                  const short* __restrict__ B,
                                                  void* __restrict__ Cout,
                                                  int K, long sA, long sB, long sC,
                                                  int ldc) {
  int bx, by;
  if (SWZGRID) {
    // chunked XCD map for the 32x12 QKV grid: XCD j owns an 8(bx) x 6(by) rectangle
    const int j = (int)blockIdx.x & 7, i = (int)blockIdx.x >> 3;  // i in [0,48)
    bx = (j & 3) * 8 + (i & 7);
    by = (j >> 2) * 6 + (i >> 3);
  } else {
    bx = blockIdx.x; by = blockIdx.y;
  }
  const int bz = blockIdx.z;
  if (CSKIP && by > bx) return;  // fully-masked causal block

  const char* Ab = (const char*)(A + bz * sA + (long)bx * 256 * K);
  const char* Bb = (const char*)(B + bz * sB + (long)by * 256 * K);
  const long ldb = (long)K * 2;  // row stride in bytes

  __shared__ __align__(16) char smem[131072];

  const int tid = threadIdx.x;
  const int lane = tid & 63, wid = tid >> 6;
  const int wm = wid >> 2, wn = wid & 3;         // 2x4 wave grid
  const int frow = lane & 15, kgrp = lane >> 4;  // MFMA fragment indices

  // staging addresses
  const long soff0 = (long)(tid & 255) * ldb + ((tid >> 8) << 4);  // + h*64 (+32 for s=1)
  const int sdst = tid * 16;                                       // + s*8192 + ring base
  // read addresses (within slot): kgrp*4096 + row*16
  const int aoff = kgrp * 4096 + (wm * 128 + frow) * 16;           // + mi*256
  const int boff = 65536 + kgrp * 4096 + (wn * 64 + frow) * 16;    // + nh*512 + ni*256

  int kt_end = K >> 6;
  if (KLIM) { int lim = (bx + 1) << 2; if (lim < kt_end) kt_end = lim; }
  const int HK = kt_end * 2;  // number of k-halves

  f32x4 acc[8][4];
  const f32x4 zero = {0.f, 0.f, 0.f, 0.f};
  #pragma unroll
  for (int mi = 0; mi < 8; ++mi)
    #pragma unroll
    for (int ni = 0; ni < 4; ++ni) acc[mi][ni] = zero;

  auto STAGE = [&](int mat, int h) {
    const char* src = (mat ? Bb : Ab) + soff0 + h * 64;
    char* dst = (char*)smem + mat * 65536 + (h & 3) * 16384 + sdst;
    async16(src, dst);
    async16(src + 32, dst + 8192);
  };

  // prologue: k-halves 0,1,2 (A+B each); steady-state invariant: last 2 slot-matrices
  // may remain in flight across a boundary
  STAGE(0, 0); STAGE(1, 0); STAGE(0, 1); STAGE(1, 1); STAGE(0, 2); STAGE(1, 2);
  asm volatile("s_waitcnt vmcnt(4)" ::: "memory");  // slots 0,1 landed
  FENCE_BAR();

  s16x8 aA[8], bB[2];
  for (int t = 0; t < kt_end; ++t) {
    #pragma unroll
    for (int ks = 0; ks < 2; ++ks) {
      const int h = 2 * t + ks;
      const int sa = (h & 3) << 14;
      const int hs = 2 * t + 3 + ks;  // stage target k-half

      // ---- phase nh=0: stage A[hs]; read A-frags + B-frags(nh0) ----
      if (hs < HK) STAGE(0, hs);
      #pragma unroll
      for (int mi = 0; mi < 8; ++mi)
        aA[mi] = *(const s16x8*)(smem + sa + aoff + mi * 256);
      #pragma unroll
      for (int ni = 0; ni < 2; ++ni)
        bB[ni] = *(const s16x8*)(smem + sa + boff + ni * 256);
      FENCE_BAR();
      MFMA_PHASE(0);
      FENCE_BAR();

      // ---- phase nh=1: stage B[hs]; read B-frags(nh1), A regs reused ----
      if (hs < HK) STAGE(1, hs);
      #pragma unroll
      for (int ni = 0; ni < 2; ++ni)
        bB[ni] = *(const s16x8*)(smem + sa + boff + 512 + ni * 256);
      FENCE_BAR();
      MFMA_PHASE(1);
      if (ks == 1) {  // K-tile boundary: counted wait (drain only near the tail)
        if (t >= kt_end - 2) asm volatile("s_waitcnt vmcnt(0)" ::: "memory");
        else                 asm volatile("s_waitcnt vmcnt(4)" ::: "memory");
      }
      FENCE_BAR();
    }
  }

  // epilogue: C/D frag layout col=frow, row=kgrp*4+r (m89-verified, conventions
  // identical to the round-2..6 passing kernels)
  const int row0 = bx * 256 + wm * 128;
  const int col0 = by * 256 + wn * 64;
  #pragma unroll
  for (int mi = 0; mi < 8; ++mi) {
    #pragma unroll
    for (int ni = 0; ni < 4; ++ni) {
      #pragma unroll
      for (int r = 0; r < 4; ++r) {
        const int row = row0 + mi * 16 + kgrp * 4 + r;
        const int col = col0 + ni * 16 + frow;
        const float v = acc[mi][ni][r];
        if (MODE == 2) {
          ((_Float16*)Cout)[bz * sC + (long)row * ldc + col] = (_Float16)v;
        } else if (MODE == 3) {
          ((float*)Cout)[bz * sC + (long)row * ldc + col] = v;
        } else {  // MODE 4: fused QKV; row=(b,t); col<1024 Q, <2048 K, else V^T
          const long QK = (long)NB * CTX * DIM;
          const int colr = col & 1023;
          long off;
          if (col < 2048) {
            off = (long)(col >> 10) * QK + (long)row * DIM + colr;
          } else {
            off = 2 * QK + (long)(row >> 11) * ((long)DIM * CTX) +
                  (long)colr * CTX + (row & (CTX - 1));
          }
          ((short*)Cout)[off] = f2bf(v);
        }
      }
    }
  }
}

// ---------------- causal softmax, in place: S fp16 -> P bf16 ----------------
// Writes P (incl. exact zeros) out to the 256-block boundary so the 256-row PV
// blocks never read unwritten workspace.
__global__ __launch_bounds__(256) void softmax_causal(void* __restrict__ Sbuf) {
  const int r = blockIdx.x, b = blockIdx.y;
  const long base = (long)b * CTX * CTX + (long)r * CTX;
  _Float16* S = (_Float16*)Sbuf + base;
  short* P = (short*)Sbuf + base;
  const int tid = threadIdx.x;
  const int lane = tid & 63, wid = tid >> 6;
  const int c0 = tid * 8;
  const int ncol = ((r >> 8) + 1) << 8;  // 256-aligned causal boundary
  const float scale = 0.03125f;  // 1/sqrt(1024)

  float v[8];
  if (c0 <= r) {
    _Float16 h[8];
    *(int4*)h = *(const int4*)&S[c0];
    #pragma unroll
    for (int j = 0; j < 8; ++j)
      v[j] = (c0 + j <= r) ? (float)h[j] * scale : -INFINITY;
  } else {
    #pragma unroll
    for (int j = 0; j < 8; ++j) v[j] = -INFINITY;
  }
  float m = -INFINITY;
  #pragma unroll
  for (int j = 0; j < 8; ++j) m = fmaxf(m, v[j]);
  #pragma unroll
  for (int off = 32; off >= 1; off >>= 1) m = fmaxf(m, __shfl_xor(m, off));
  __shared__ float redm[4], reds[4];
  if (lane == 0) redm[wid] = m;
  __syncthreads();
  m = fmaxf(fmaxf(redm[0], redm[1]), fmaxf(redm[2], redm[3]));

  float p[8];
  float s = 0.f;
  #pragma unroll
  for (int j = 0; j < 8; ++j) {
    p[j] = exp2f((v[j] - m) * 1.44269504f);
    s += p[j];
  }
  #pragma unroll
  for (int off = 32; off >= 1; off >>= 1) s += __shfl_xor(s, off);
  if (lane == 0) reds[wid] = s;
  __syncthreads();
  s = reds[0] + reds[1] + reds[2] + reds[3];
  const float inv = 1.0f / s;

  if (c0 < ncol) {
    short o[8];
    #pragma unroll
    for (int j = 0; j < 8; ++j) o[j] = f2bf(p[j] * inv);
    *(int4*)&P[c0] = *(int4*)o;
  }
}

// ---------------- launch ----------------
extern "C" void kernel_launch(void* const* d_in, const int* in_sizes, int n_in,
                              void* d_out, int out_size, void* d_ws, size_t ws_size,
                              hipStream_t stream) {
  (void)in_sizes; (void)n_in; (void)out_size; (void)ws_size;
  const float* x  = (const float*)d_in[0];
  const float* Wq = (const float*)d_in[1];
  const float* Wk = (const float*)d_in[2];
  const float* Wv = (const float*)d_in[3];

  const long MB = 1024 * 1024;
  char* ws = (char*)d_ws;
  short* xb = (short*)(ws + 0);         // 16 MB  [8192][1024] bf16
  short* WT = (short*)(ws + 16 * MB);   //  6 MB  [3072][1024] bf16 (Wq^T,Wk^T,Wv^T)
  short* Qb = (short*)(ws + 24 * MB);   // 16 MB  [4][2048][1024] bf16
  short* Kb = (short*)(ws + 40 * MB);   // 16 MB  (contiguous after Qb)
  short* Vt = (short*)(ws + 56 * MB);   // 16 MB  [4][1024 e][2048 t] bf16 (V^T)
  void*  S  = (void*)(ws + 72 * MB);    // 32 MB  [4][2048][2048] fp16 -> bf16 P

  // 1) x -> bf16
  cvt_x<<<4096, 256, 0, stream>>>(x, xb, (long)NB * CTX * DIM / 8);
  // 2) W -> W^T bf16 (stacked)
  cvt_wT<<<dim3(32, 32, 3), dim3(32, 8), 0, stream>>>(Wq, Wk, Wv, WT);
  // 3) fused QKV: [8192,1024] @ [3072,1024]^T, 32x12=384 blocks, chunked XCD map
  gemm256<4, false, false, true><<<384, 512, 0, stream>>>(
      xb, WT, Qb, DIM, 0, 0, 0, DIM);
  // 4) S = Q K^T -> fp16, lower-triangular 256-blocks only
  gemm256<2, true, false, false><<<dim3(8, 8, NB), 512, 0, stream>>>(
      Qb, Kb, S, DIM, (long)CTX * DIM, (long)CTX * DIM, (long)CTX * CTX, CTX);
  // 5) causal softmax in place (fp16 scores -> bf16 P, zero-filled to 256 boundary)
  softmax_causal<<<dim3(CTX, NB), 256, 0, stream>>>(S);
  // 6) O = P V via V^T (M=2048, N=1024, K=2048), K-tiles causally limited
  gemm256<3, false, true, false><<<dim3(8, 4, NB), 512, 0, stream>>>(
      (short*)S, Vt, d_out, CTX, (long)CTX * CTX, (long)DIM * CTX, (long)CTX * DIM, DIM);
}